// Round 5
// baseline (133.102 us; speedup 1.0000x reference)
//
#include <hip/hip_runtime.h>
#include <hip/hip_bf16.h>
#include <math.h>

#define NB 32
#define SEQT 512
#define DDIM 16
#define NWIN 510
#define NTOT (NB*NWIN)      // 16320
#define SLOPE 0.2f
#define TW 16               // windows per block tile
#define NTILE (NTOT/TW)     // 1020 (exact)

typedef __attribute__((ext_vector_type(8))) short sh8;   // 8 bf16
typedef __attribute__((ext_vector_type(4))) float f4;

// ws byte offsets
#define W0B_OFF 0            // bf16 [16][64][32]   (k = 0..31 only)
#define W1B_OFF 65536        // bf16 [16][64][64]
#define W2B_OFF 196608       // bf16 [16][64][64]
#define WCOL_OFF 327680      // f32  [16][64]  = W0[d][h][32]
#define RED_OFF 331776       // f32  [1020][2]
#define NPREP 164864

static __device__ __forceinline__ unsigned short bfb(float f){
    union { __hip_bfloat16 h; unsigned short u; } cv;
    cv.h = __float2bfloat16(f);
    return cv.u;
}
static __device__ __forceinline__ unsigned pk2(float a, float b){
    return (unsigned)bfb(a) | ((unsigned)bfb(b) << 16);
}

__global__ void prep(const float* __restrict__ W0, const float* __restrict__ W1,
                     const float* __restrict__ W2, unsigned char* __restrict__ wsb){
    int e = blockIdx.x*256 + threadIdx.x;
    if (e < 32768){
        unsigned short* W0b = (unsigned short*)(wsb + W0B_OFF);
        int d = e >> 11, r = e & 2047, h = r >> 5, k = r & 31;
        W0b[e] = bfb(W0[(d*64 + h)*33 + k]);
    } else if (e < 98304){
        ((unsigned short*)(wsb + W1B_OFF))[e - 32768] = bfb(W1[e - 32768]);
    } else if (e < 163840){
        ((unsigned short*)(wsb + W2B_OFF))[e - 98304] = bfb(W2[e - 98304]);
    } else if (e < NPREP){
        int i = e - 163840;
        int d = i >> 6, h = i & 63;
        ((float*)(wsb + WCOL_OFF))[i] = W0[(d*64 + h)*33 + 32];
    }
}

__global__ __launch_bounds__(1024, 8) void mlp(
    const float* __restrict__ x,
    const float* __restrict__ bias0, const float* __restrict__ bias1,
    const float* __restrict__ bias2,
    const float* __restrict__ Wout, const float* __restrict__ boutp,
    const unsigned char* __restrict__ wsb,
    float* __restrict__ red, float* __restrict__ out)
{
    // one block = 16 windows x all 16 d.  wave w handles d = w for the 16 windows.
    __shared__ __align__(16) unsigned char bufC[TW*64];        // input rows (K=32), shared by all waves
    __shared__ __align__(16) unsigned char bufA[16*TW*128];    // per-wave h1->h2 (32 KB)
    __shared__ __align__(16) unsigned char bufB[16*TW*128];    // per-wave t1->t2 (32 KB)
    __shared__ float outbuf[TW][DDIM];
    __shared__ float wred[16][2];

    const int tid  = threadIdx.x;
    const int lane = tid & 63;
    const int w    = tid >> 6;        // wave id == d
    const int d    = w;
    const int nl   = lane & 15;
    const int hi   = lane >> 4;
    const int row  = 16*w + nl;       // private row in bufA/bufB
    const int tile = blockIdx.x;
    const int rsw  = (nl & 7) << 4;   // XOR swizzle for this lane's row

    const unsigned char* W0b = wsb + W0B_OFF + d*4096;
    const unsigned char* W1b = wsb + W1B_OFF + d*8192;
    const unsigned char* W2b = wsb + W2B_OFF + d*8192;

    // ---- preload twice-used weight fragments (live in AGPRs) ----
    sh8 w1f[2][4], w2f[2][4];
    #pragma unroll
    for (int ks=0; ks<2; ++ks)
        #pragma unroll
        for (int t=0; t<4; ++t){
            int off = ((16*t+nl)*64 + 32*ks + 8*hi)*2;
            w1f[ks][t] = *(const sh8*)&W1b[off];
            w2f[ks][t] = *(const sh8*)&W2b[off];
        }

    // ---- wave 0 stages the shared input tile (16 rows x 32 bf16) ----
    if (w == 0){
        int rowg = lane >> 2;         // 16 rows x 4 lanes
        int q = lane & 3;
        int ns = tile*TW + rowg;
        int bs = ns / NWIN, ts = ns - bs*NWIN;
        const float* gp = x + (size_t)(bs*SEQT + ts)*DDIM + 8*q;
        float4 v0 = ((const float4*)gp)[0];
        float4 v1 = ((const float4*)gp)[1];
        uint4 pk;
        pk.x = pk2(v0.x, v0.y); pk.y = pk2(v0.z, v0.w);
        pk.z = pk2(v1.x, v1.y); pk.w = pk2(v1.z, v1.w);
        *(uint4*)&bufC[rowg*64 + 16*(q ^ (rowg & 3))] = pk;
    }

    // per-lane window & current-step feature
    const int n = tile*TW + nl;
    const int b = n / NWIN, tn = n - b*NWIN;
    const float xx = x[(size_t)(b*SEQT + tn + 2)*DDIM + d];

    __syncthreads();

    f4 accA[4], accB[4];

    // ---------------- L1 (K=32 MFMA + fp32 rank-1 for col 32) ----------------
    #pragma unroll
    for (int t=0;t<4;++t){
        float4 bv = *(const float4*)(bias0 + d*64 + 16*t + 4*hi);
        accA[t][0]=bv.x; accA[t][1]=bv.y; accA[t][2]=bv.z; accA[t][3]=bv.w;
    }
    {
        sh8 bfrag = *(const sh8*)&bufC[nl*64 + 16*(hi ^ (nl & 3))];
        #pragma unroll
        for (int t=0;t<4;++t){
            sh8 afrag = *(const sh8*)&W0b[((16*t+nl)*32 + 8*hi)*2];
            accA[t] = __builtin_amdgcn_mfma_f32_16x16x32_bf16(afrag, bfrag, accA[t], 0,0,0);
        }
    }
    // epilogue: rank-1, act -> bufA ; t1 = deriv1.*wcol -> bufB
    {
        const float* wcolp = (const float*)(wsb + WCOL_OFF) + d*64;
        #pragma unroll
        for (int t=0;t<4;++t){
            float4 wv = *(const float4*)(wcolp + 16*t + 4*hi);
            float wc[4] = {wv.x, wv.y, wv.z, wv.w};
            float v[4], tv[4];
            #pragma unroll
            for (int r=0;r<4;++r){
                float a = fmaf(wc[r], xx, accA[t][r]);
                v[r]  = fmaxf(a, SLOPE*a);
                tv[r] = (a >= 0.f) ? wc[r] : SLOPE*wc[r];
            }
            uint2 ph; ph.x = pk2(v[0],v[1]);  ph.y = pk2(v[2],v[3]);
            *(uint2*)&bufA[row*128 + ((32*t + 8*hi) ^ rsw)] = ph;
            uint2 pt; pt.x = pk2(tv[0],tv[1]); pt.y = pk2(tv[2],tv[3]);
            *(uint2*)&bufB[row*128 + ((32*t + 8*hi) ^ rsw)] = pt;
        }
    }

    // ---------------- L2: h2 = act(W1 h1 + b1)  (bufA in-place) ----------------
    #pragma unroll
    for (int t=0;t<4;++t){
        float4 bv = *(const float4*)(bias1 + d*64 + 16*t + 4*hi);
        accA[t][0]=bv.x; accA[t][1]=bv.y; accA[t][2]=bv.z; accA[t][3]=bv.w;
    }
    #pragma unroll
    for (int ks=0; ks<2; ++ks){
        sh8 bfrag = *(const sh8*)&bufA[row*128 + ((64*ks + 16*hi) ^ rsw)];
        #pragma unroll
        for (int t=0;t<4;++t)
            accA[t] = __builtin_amdgcn_mfma_f32_16x16x32_bf16(w1f[ks][t], bfrag, accA[t], 0,0,0);
    }
    #pragma unroll
    for (int t=0;t<4;++t){
        float v[4];
        #pragma unroll
        for (int r=0;r<4;++r){
            float a = accA[t][r];
            v[r] = fmaxf(a, SLOPE*a);
            accA[t][r] = v[r];                 // keep h2 (sign carries deriv2)
        }
        uint2 ph; ph.x = pk2(v[0],v[1]); ph.y = pk2(v[2],v[3]);
        *(uint2*)&bufA[row*128 + ((32*t + 8*hi) ^ rsw)] = ph;
    }

    // ---------------- T2: t2 = d2 .* (W1 t1)  (bufB in-place) ----------------
    #pragma unroll
    for (int t=0;t<4;++t) accB[t] = (f4){0.f,0.f,0.f,0.f};
    #pragma unroll
    for (int ks=0; ks<2; ++ks){
        sh8 bfrag = *(const sh8*)&bufB[row*128 + ((64*ks + 16*hi) ^ rsw)];
        #pragma unroll
        for (int t=0;t<4;++t)
            accB[t] = __builtin_amdgcn_mfma_f32_16x16x32_bf16(w1f[ks][t], bfrag, accB[t], 0,0,0);
    }
    #pragma unroll
    for (int t=0;t<4;++t){
        float v[4];
        #pragma unroll
        for (int r=0;r<4;++r){
            float a = accB[t][r];
            v[r] = (accA[t][r] >= 0.f) ? a : SLOPE*a;   // sign(h2) == sign(a2)
        }
        uint2 pt; pt.x = pk2(v[0],v[1]); pt.y = pk2(v[2],v[3]);
        *(uint2*)&bufB[row*128 + ((32*t + 8*hi) ^ rsw)] = pt;
    }

    // ---------------- L3: h3 = act(W2 h2 + b2)  (stays in regs) ----------------
    #pragma unroll
    for (int t=0;t<4;++t){
        float4 bv = *(const float4*)(bias2 + d*64 + 16*t + 4*hi);
        accA[t][0]=bv.x; accA[t][1]=bv.y; accA[t][2]=bv.z; accA[t][3]=bv.w;
    }
    #pragma unroll
    for (int ks=0; ks<2; ++ks){
        sh8 bfrag = *(const sh8*)&bufA[row*128 + ((64*ks + 16*hi) ^ rsw)];
        #pragma unroll
        for (int t=0;t<4;++t)
            accA[t] = __builtin_amdgcn_mfma_f32_16x16x32_bf16(w2f[ks][t], bfrag, accA[t], 0,0,0);
    }
    #pragma unroll
    for (int t=0;t<4;++t)
        #pragma unroll
        for (int r=0;r<4;++r){
            float a = accA[t][r];
            accA[t][r] = fmaxf(a, SLOPE*a);    // h3 (sign carries deriv3)
        }

    // ---------------- T3: t3raw = W2 t2  (regs) ----------------
    #pragma unroll
    for (int t=0;t<4;++t) accB[t] = (f4){0.f,0.f,0.f,0.f};
    #pragma unroll
    for (int ks=0; ks<2; ++ks){
        sh8 bfrag = *(const sh8*)&bufB[row*128 + ((64*ks + 16*hi) ^ rsw)];
        #pragma unroll
        for (int t=0;t<4;++t)
            accB[t] = __builtin_amdgcn_mfma_f32_16x16x32_bf16(w2f[ks][t], bfrag, accB[t], 0,0,0);
    }

    // ---------------- head + logdet ----------------
    float res = 0.f, dres = 0.f;
    #pragma unroll
    for (int t=0;t<4;++t){
        float4 ov = *(const float4*)(Wout + d*64 + 16*t + 4*hi);
        float wo[4] = {ov.x, ov.y, ov.z, ov.w};
        #pragma unroll
        for (int r=0;r<4;++r){
            float h3 = accA[t][r];
            res = fmaf(wo[r], h3, res);
            float a = accB[t][r];
            float tv = (h3 >= 0.f) ? a : SLOPE*a;
            dres = fmaf(wo[r], tv, dres);
        }
    }
    res  += __shfl_xor(res, 16);  res  += __shfl_xor(res, 32);
    dres += __shfl_xor(dres, 16); dres += __shfl_xor(dres, 32);
    res += boutp[d];
    if (hi == 0) outbuf[nl][d] = res;

    float logabs = __logf(fabsf(dres));

    // per-wave deterministic reduction (split by batch bucket)
    {
        int cb0 = (tile*TW) / NWIN;
        float v0 = (b == cb0)     ? logabs : 0.f;
        float v1 = (b == cb0 + 1) ? logabs : 0.f;
        #pragma unroll
        for (int s = 1; s < 16; s <<= 1){
            v0 += __shfl_xor(v0, s);
            v1 += __shfl_xor(v1, s);
        }
        if (lane == 0){ wred[w][0] = v0; wred[w][1] = v1; }
    }
    __syncthreads();

    // coalesced output store: 256 consecutive floats
    if (tid < TW*DDIM)
        out[(size_t)tile*(TW*DDIM) + tid] = outbuf[tid >> 4][tid & 15];
    if (tid == 0){
        float s0 = 0.f, s1 = 0.f;
        #pragma unroll
        for (int k=0;k<16;++k){ s0 += wred[k][0]; s1 += wred[k][1]; }
        red[tile*2 + 0] = s0;
        red[tile*2 + 1] = s1;
    }
}

__global__ void final_red(const float* __restrict__ red, float* __restrict__ sld){
    __shared__ float r[256];
    const int b = blockIdx.x;
    const int t = threadIdx.x;
    float s = 0.f;
    for (int tl = t; tl < NTILE; tl += 256){
        int cb0 = (tl*TW)/NWIN;
        if (cb0     == b) s += red[tl*2 + 0];
        if (cb0 + 1 == b) s += red[tl*2 + 1];
    }
    r[t] = s;
    __syncthreads();
    for (int st = 128; st > 0; st >>= 1){
        if (t < st) r[t] += r[t + st];
        __syncthreads();
    }
    if (t == 0) sld[b] = r[0];
}

extern "C" void kernel_launch(void* const* d_in, const int* in_sizes, int n_in,
                              void* d_out, int out_size, void* d_ws, size_t ws_size,
                              hipStream_t stream) {
    const float* x    = (const float*)d_in[0];
    const float* W0   = (const float*)d_in[1];
    const float* b0   = (const float*)d_in[2];
    const float* W1   = (const float*)d_in[3];
    const float* b1   = (const float*)d_in[4];
    const float* W2   = (const float*)d_in[5];
    const float* b2   = (const float*)d_in[6];
    const float* Wout = (const float*)d_in[7];
    const float* bout = (const float*)d_in[8];
    float* out = (float*)d_out;
    unsigned char* wsb = (unsigned char*)d_ws;

    prep<<<(NPREP + 255)/256, 256, 0, stream>>>(W0, W1, W2, wsb);

    mlp<<<NTILE, 1024, 0, stream>>>(x, b0, b1, b2, Wout, bout, wsb,
                                    (float*)(wsb + RED_OFF), out);

    final_red<<<NB, 256, 0, stream>>>((const float*)(wsb + RED_OFF),
                                      out + (size_t)NTOT*DDIM);
}

// Round 6
// 66.423 us; speedup vs baseline: 2.0039x; 2.0039x over previous
//
#include <hip/hip_runtime.h>
#include <hip/hip_bf16.h>
#include <math.h>

#define NB 32
#define SEQT 512
#define DDIM 16
#define NWIN 510
#define NTOT (NB*NWIN)      // 16320
#define SLOPE 0.2f
#define NR 64               // windows per block
#define NCH (NTOT/NR)       // 255 (exact)

typedef __attribute__((ext_vector_type(8))) short sh8;   // 8 bf16
typedef __attribute__((ext_vector_type(4))) float f4;

// ws byte offsets
#define W0B_OFF 0            // bf16 [16][64][32]   (k = 0..31 only)
#define W1B_OFF 65536        // bf16 [16][64][64]
#define W2B_OFF 196608       // bf16 [16][64][64]
#define WCOL_OFF 327680      // f32  [16][64]  = W0[d][h][32]
#define RED_OFF 331776       // f32  [255][4][16][2]  (130560 B)
#define RES_OFF 462336       // f32  [255][16][64]    (1044480 B)
#define NPREP 164864

static __device__ __forceinline__ unsigned short bfb(float f){
    union { __hip_bfloat16 h; unsigned short u; } cv;
    cv.h = __float2bfloat16(f);
    return cv.u;
}
static __device__ __forceinline__ unsigned pk2(float a, float b){
    return (unsigned)bfb(a) | ((unsigned)bfb(b) << 16);
}

__global__ void prep(const float* __restrict__ W0, const float* __restrict__ W1,
                     const float* __restrict__ W2, unsigned char* __restrict__ wsb){
    int e = blockIdx.x*256 + threadIdx.x;
    if (e < 32768){
        unsigned short* W0b = (unsigned short*)(wsb + W0B_OFF);
        int d = e >> 11, r = e & 2047, h = r >> 5, k = r & 31;
        W0b[e] = bfb(W0[(d*64 + h)*33 + k]);
    } else if (e < 98304){
        ((unsigned short*)(wsb + W1B_OFF))[e - 32768] = bfb(W1[e - 32768]);
    } else if (e < 163840){
        ((unsigned short*)(wsb + W2B_OFF))[e - 98304] = bfb(W2[e - 98304]);
    } else if (e < NPREP){
        int i = e - 163840;
        int d = i >> 6, h = i & 63;
        ((float*)(wsb + WCOL_OFF))[i] = W0[(d*64 + h)*33 + 32];
    }
}

__global__ __launch_bounds__(256, 5) void mlp(
    const float* __restrict__ x,
    const float* __restrict__ bias0, const float* __restrict__ bias1,
    const float* __restrict__ bias2,
    const float* __restrict__ Wout, const float* __restrict__ boutp,
    const unsigned char* __restrict__ wsb,
    float* __restrict__ red, float* __restrict__ resb)
{
    // barrier-free: every wave touches only rows [16w, 16w+16)
    __shared__ __align__(16) unsigned char bufC[NR*64];    // input rows (K=32)
    __shared__ __align__(16) unsigned char bufA[NR*128];   // h1 -> h2 (in-place)
    __shared__ __align__(16) unsigned char bufB[NR*128];   // t1 -> t2 (in-place)

    const int tid  = threadIdx.x;
    const int lane = tid & 63;
    const int w    = tid >> 6;
    const int nl   = lane & 15;
    const int hi   = lane >> 4;
    const int row  = 16*w + nl;
    const int chunk = blockIdx.x;
    const int d     = blockIdx.y;
    const int rsw   = (nl & 7) << 4;

    const unsigned char* W0b = wsb + W0B_OFF + d*4096;
    const unsigned char* W1b = wsb + W1B_OFF + d*8192;
    const unsigned char* W2b = wsb + W2B_OFF + d*8192;

    // ---- stage input (wave-private rows): cols 0..31 = yy ----
    {
        int rowg = 16*w + (lane>>2);
        int q = lane & 3;
        int ns = chunk*NR + rowg;
        int bs = ns / NWIN, ts = ns - bs*NWIN;
        const float* gp = x + (size_t)(bs*SEQT + ts)*DDIM + 8*q;
        float4 v0 = ((const float4*)gp)[0];
        float4 v1 = ((const float4*)gp)[1];
        uint4 pk;
        pk.x = pk2(v0.x, v0.y); pk.y = pk2(v0.z, v0.w);
        pk.z = pk2(v1.x, v1.y); pk.w = pk2(v1.z, v1.w);
        *(uint4*)&bufC[rowg*64 + 16*(q ^ (rowg & 3))] = pk;
    }

    const int n = chunk*NR + row;
    const int b = n / NWIN, tn = n - b*NWIN;
    const float xx = x[(size_t)(b*SEQT + tn + 2)*DDIM + d];

    f4 accA[4], accB[4];

    // ---------------- L1 (K=32 MFMA + fp32 rank-1 for col 32) ----------------
    #pragma unroll
    for (int t=0;t<4;++t){
        float4 bv = *(const float4*)(bias0 + d*64 + 16*t + 4*hi);
        accA[t][0]=bv.x; accA[t][1]=bv.y; accA[t][2]=bv.z; accA[t][3]=bv.w;
    }
    {
        sh8 bfrag = *(const sh8*)&bufC[row*64 + 16*(hi ^ (nl & 3))];
        #pragma unroll
        for (int t=0;t<4;++t){
            sh8 afrag = *(const sh8*)&W0b[((16*t+nl)*32 + 8*hi)*2];
            accA[t] = __builtin_amdgcn_mfma_f32_16x16x32_bf16(afrag, bfrag, accA[t], 0,0,0);
        }
    }
    // epilogue: rank-1, act -> bufA ; t1 = deriv1.*wcol -> bufB
    {
        const float* wcolp = (const float*)(wsb + WCOL_OFF) + d*64;
        #pragma unroll
        for (int t=0;t<4;++t){
            float4 wv = *(const float4*)(wcolp + 16*t + 4*hi);
            float wc[4] = {wv.x, wv.y, wv.z, wv.w};
            float v[4], tv[4];
            #pragma unroll
            for (int r=0;r<4;++r){
                float a = fmaf(wc[r], xx, accA[t][r]);
                v[r]  = fmaxf(a, SLOPE*a);
                tv[r] = (a >= 0.f) ? wc[r] : SLOPE*wc[r];
            }
            uint2 ph; ph.x = pk2(v[0],v[1]);  ph.y = pk2(v[2],v[3]);
            *(uint2*)&bufA[row*128 + ((32*t + 8*hi) ^ rsw)] = ph;
            uint2 pt; pt.x = pk2(tv[0],tv[1]); pt.y = pk2(tv[2],tv[3]);
            *(uint2*)&bufB[row*128 + ((32*t + 8*hi) ^ rsw)] = pt;
        }
    }

    // ---------------- G2: L2 fwd + T2 tangent, shared A-fragments ----------------
    #pragma unroll
    for (int t=0;t<4;++t){
        float4 bv = *(const float4*)(bias1 + d*64 + 16*t + 4*hi);
        accA[t][0]=bv.x; accA[t][1]=bv.y; accA[t][2]=bv.z; accA[t][3]=bv.w;
        accB[t] = (f4){0.f,0.f,0.f,0.f};
    }
    __builtin_amdgcn_s_setprio(1);
    #pragma unroll
    for (int ks=0; ks<2; ++ks){
        sh8 bfA = *(const sh8*)&bufA[row*128 + ((64*ks + 16*hi) ^ rsw)];
        sh8 bfB = *(const sh8*)&bufB[row*128 + ((64*ks + 16*hi) ^ rsw)];
        #pragma unroll
        for (int t=0;t<4;++t){
            sh8 af = *(const sh8*)&W1b[((16*t+nl)*64 + 32*ks + 8*hi)*2];
            accA[t] = __builtin_amdgcn_mfma_f32_16x16x32_bf16(af, bfA, accA[t], 0,0,0);
            accB[t] = __builtin_amdgcn_mfma_f32_16x16x32_bf16(af, bfB, accB[t], 0,0,0);
        }
    }
    __builtin_amdgcn_s_setprio(0);
    // E2: h2 -> bufA, t2 -> bufB
    #pragma unroll
    for (int t=0;t<4;++t){
        float v[4], tv[4];
        #pragma unroll
        for (int r=0;r<4;++r){
            float a = accA[t][r];
            v[r] = fmaxf(a, SLOPE*a);
            float g = accB[t][r];
            tv[r] = (a >= 0.f) ? g : SLOPE*g;
        }
        uint2 ph; ph.x = pk2(v[0],v[1]); ph.y = pk2(v[2],v[3]);
        *(uint2*)&bufA[row*128 + ((32*t + 8*hi) ^ rsw)] = ph;
        uint2 pt; pt.x = pk2(tv[0],tv[1]); pt.y = pk2(tv[2],tv[3]);
        *(uint2*)&bufB[row*128 + ((32*t + 8*hi) ^ rsw)] = pt;
    }

    // ---------------- G3: L3 fwd + T3 tangent, shared A-fragments ----------------
    #pragma unroll
    for (int t=0;t<4;++t){
        float4 bv = *(const float4*)(bias2 + d*64 + 16*t + 4*hi);
        accA[t][0]=bv.x; accA[t][1]=bv.y; accA[t][2]=bv.z; accA[t][3]=bv.w;
        accB[t] = (f4){0.f,0.f,0.f,0.f};
    }
    __builtin_amdgcn_s_setprio(1);
    #pragma unroll
    for (int ks=0; ks<2; ++ks){
        sh8 bfA = *(const sh8*)&bufA[row*128 + ((64*ks + 16*hi) ^ rsw)];
        sh8 bfB = *(const sh8*)&bufB[row*128 + ((64*ks + 16*hi) ^ rsw)];
        #pragma unroll
        for (int t=0;t<4;++t){
            sh8 af = *(const sh8*)&W2b[((16*t+nl)*64 + 32*ks + 8*hi)*2];
            accA[t] = __builtin_amdgcn_mfma_f32_16x16x32_bf16(af, bfA, accA[t], 0,0,0);
            accB[t] = __builtin_amdgcn_mfma_f32_16x16x32_bf16(af, bfB, accB[t], 0,0,0);
        }
    }
    __builtin_amdgcn_s_setprio(0);

    // ---------------- head + logdet ----------------
    float res = 0.f, dres = 0.f;
    #pragma unroll
    for (int t=0;t<4;++t){
        float4 ov = *(const float4*)(Wout + d*64 + 16*t + 4*hi);
        float wo[4] = {ov.x, ov.y, ov.z, ov.w};
        #pragma unroll
        for (int r=0;r<4;++r){
            float a  = accA[t][r];
            float h3 = fmaxf(a, SLOPE*a);
            res = fmaf(wo[r], h3, res);
            float g = accB[t][r];
            float tv = (a >= 0.f) ? g : SLOPE*g;
            dres = fmaf(wo[r], tv, dres);
        }
    }
    res  += __shfl_xor(res, 16);  res  += __shfl_xor(res, 32);
    dres += __shfl_xor(dres, 16); dres += __shfl_xor(dres, 32);
    res += boutp[d];
    // block-owned 64B line: no cross-XCD write sharing
    if (hi == 0)
        resb[(size_t)(chunk*16 + d)*64 + row] = res;

    float logabs = __logf(fabsf(dres));

    // per-wave deterministic reduction (split by batch bucket)
    {
        int cb0 = (chunk*NR) / NWIN;
        float v0 = (b == cb0)     ? logabs : 0.f;
        float v1 = (b == cb0 + 1) ? logabs : 0.f;
        #pragma unroll
        for (int s = 1; s < 16; s <<= 1){
            v0 += __shfl_xor(v0, s);
            v1 += __shfl_xor(v1, s);
        }
        if (lane == 0){
            red[((size_t)(chunk*4 + w)*16 + d)*2 + 0] = v0;
            red[((size_t)(chunk*4 + w)*16 + d)*2 + 1] = v1;
        }
    }
}

// ws_res [chunk][d][row] -> out [n][d], fully coalesced writes
__global__ void scatter_out(const float* __restrict__ resb, float* __restrict__ out){
    int e = blockIdx.x*256 + threadIdx.x;   // 261120 total
    int nn = e >> 4, d = e & 15;
    int chunk = nn >> 6, row = nn & 63;
    out[e] = resb[(size_t)(chunk*16 + d)*64 + row];
}

__global__ void final_red(const float* __restrict__ red, float* __restrict__ sld){
    __shared__ float pp[DDIM][16];
    const int b = blockIdx.x;
    const int tid = threadIdx.x;
    const int d = tid & 15, j = tid >> 4;
    float s = 0.f;
    for (int gw = j; gw < NCH*4; gw += 16){
        int chunk = gw >> 2;
        int cb0 = (chunk*NR)/NWIN;
        const float* r = red + ((size_t)gw*16 + d)*2;
        if (cb0     == b) s += r[0];
        if (cb0 + 1 == b) s += r[1];
    }
    pp[d][j] = s;
    __syncthreads();
    if (tid < DDIM){
        float a = 0.f;
        #pragma unroll
        for (int k=0;k<16;++k) a += pp[tid][k];
        pp[tid][0] = a;
    }
    __syncthreads();
    if (tid == 0){
        float a = 0.f;
        #pragma unroll
        for (int dd=0; dd<DDIM; ++dd) a += pp[dd][0];
        sld[b] = a;
    }
}

extern "C" void kernel_launch(void* const* d_in, const int* in_sizes, int n_in,
                              void* d_out, int out_size, void* d_ws, size_t ws_size,
                              hipStream_t stream) {
    const float* x    = (const float*)d_in[0];
    const float* W0   = (const float*)d_in[1];
    const float* b0   = (const float*)d_in[2];
    const float* W1   = (const float*)d_in[3];
    const float* b1   = (const float*)d_in[4];
    const float* W2   = (const float*)d_in[5];
    const float* b2   = (const float*)d_in[6];
    const float* Wout = (const float*)d_in[7];
    const float* bout = (const float*)d_in[8];
    float* out = (float*)d_out;
    unsigned char* wsb = (unsigned char*)d_ws;

    prep<<<(NPREP + 255)/256, 256, 0, stream>>>(W0, W1, W2, wsb);

    dim3 grid(NCH, DDIM);
    mlp<<<grid, 256, 0, stream>>>(x, b0, b1, b2, Wout, bout, wsb,
                                  (float*)(wsb + RED_OFF),
                                  (float*)(wsb + RES_OFF));

    scatter_out<<<(NTOT*DDIM)/256, 256, 0, stream>>>((const float*)(wsb + RES_OFF), out);

    final_red<<<NB, 256, 0, stream>>>((const float*)(wsb + RED_OFF),
                                      out + (size_t)NTOT*DDIM);
}

// Round 7
// 47.840 us; speedup vs baseline: 2.7822x; 1.3884x over previous
//
#include <hip/hip_runtime.h>
#include <hip/hip_bf16.h>
#include <math.h>

#define NB 32
#define SEQT 512
#define DDIM 16
#define NWIN 510
#define NTOT (NB*NWIN)      // 16320
#define SLOPE 0.2f
#define NG 128              // groups of 128 windows (last one part-dummy)

typedef __attribute__((ext_vector_type(8))) short sh8;   // 8 bf16
typedef __attribute__((ext_vector_type(4))) float f4;

// ws byte offsets
#define W0B_OFF 0            // bf16 [16][64][32]   (k = 0..31 only)
#define W1B_OFF 65536        // bf16 [16][64][64]
#define W2B_OFF 196608       // bf16 [16][64][64]
#define WCOL_OFF 327680      // f32  [16][64]  = W0[d][h][32]
#define RED_OFF 331776       // f32  [512][16][2]   (65536 B)
#define RES_OFF 397312       // f32  [128][16][128] (1 MB)
#define NPREP 164864

static __device__ __forceinline__ unsigned short bfb(float f){
    union { __hip_bfloat16 h; unsigned short u; } cv;
    cv.h = __float2bfloat16(f);
    return cv.u;
}
static __device__ __forceinline__ unsigned pk2(float a, float b){
    return (unsigned)bfb(a) | ((unsigned)bfb(b) << 16);
}

__global__ void prep(const float* __restrict__ W0, const float* __restrict__ W1,
                     const float* __restrict__ W2, unsigned char* __restrict__ wsb){
    int e = blockIdx.x*256 + threadIdx.x;
    if (e < 32768){
        unsigned short* W0b = (unsigned short*)(wsb + W0B_OFF);
        int d = e >> 11, r = e & 2047, h = r >> 5, k = r & 31;
        W0b[e] = bfb(W0[(d*64 + h)*33 + k]);
    } else if (e < 98304){
        ((unsigned short*)(wsb + W1B_OFF))[e - 32768] = bfb(W1[e - 32768]);
    } else if (e < 163840){
        ((unsigned short*)(wsb + W2B_OFF))[e - 98304] = bfb(W2[e - 98304]);
    } else if (e < NPREP){
        int i = e - 163840;
        int d = i >> 6, h = i & 63;
        ((float*)(wsb + WCOL_OFF))[i] = W0[(d*64 + h)*33 + 32];
    }
}

__global__ __launch_bounds__(256, 3) void mlp(
    const float* __restrict__ x,
    const float* __restrict__ bias0, const float* __restrict__ bias1,
    const float* __restrict__ bias2,
    const float* __restrict__ Wout, const float* __restrict__ boutp,
    const unsigned char* __restrict__ wsb,
    float* __restrict__ red, float* __restrict__ resb)
{
    // barrier-free: wave w owns rows [32w, 32w+32) of bufA/bufB.
    // each wave runs TWO independent 16-window instances for intra-wave ILP.
    __shared__ __align__(16) unsigned char bufA[128*128];   // h1 -> h2 (in-place), 16 KB
    __shared__ __align__(16) unsigned char bufB[128*128];   // t1 -> t2 (in-place), 16 KB

    const int tid  = threadIdx.x;
    const int lane = tid & 63;
    const int w    = tid >> 6;
    const int nl   = lane & 15;
    const int hi   = lane >> 4;
    const int rsw  = (nl & 7) << 4;
    const int g    = blockIdx.x;
    const int d    = blockIdx.y;

    const int r0 = 32*w + nl;         // instance-0 row
    const int r1 = r0 + 16;           // instance-1 row
    const int n0 = g*128 + r0;
    const int n1 = n0 + 16;
    const bool val0 = (n0 < NTOT), val1 = (n1 < NTOT);
    const int ne0 = val0 ? n0 : NTOT-1;
    const int ne1 = val1 ? n1 : NTOT-1;
    const int b0 = ne0 / NWIN, t0 = ne0 - b0*NWIN;
    const int b1 = ne1 / NWIN, t1 = ne1 - b1*NWIN;

    // ---- L1 B-fragments straight from global (f32 -> bf16, no LDS) ----
    const float* gp0 = x + (size_t)(b0*SEQT + t0)*DDIM + 8*hi;
    const float* gp1 = x + (size_t)(b1*SEQT + t1)*DDIM + 8*hi;
    float4 p00 = ((const float4*)gp0)[0], p01 = ((const float4*)gp0)[1];
    float4 p10 = ((const float4*)gp1)[0], p11 = ((const float4*)gp1)[1];
    union { uint4 u; sh8 s; } in0, in1;
    in0.u.x = pk2(p00.x,p00.y); in0.u.y = pk2(p00.z,p00.w);
    in0.u.z = pk2(p01.x,p01.y); in0.u.w = pk2(p01.z,p01.w);
    in1.u.x = pk2(p10.x,p10.y); in1.u.y = pk2(p10.z,p10.w);
    in1.u.z = pk2(p11.x,p11.y); in1.u.w = pk2(p11.z,p11.w);

    const float xx0 = x[(size_t)(b0*SEQT + t0 + 2)*DDIM + d];
    const float xx1 = x[(size_t)(b1*SEQT + t1 + 2)*DDIM + d];

    const unsigned char* W0b = wsb + W0B_OFF + d*4096;
    const unsigned char* W1b = wsb + W1B_OFF + d*8192;
    const unsigned char* W2b = wsb + W2B_OFF + d*8192;

    f4 aA0[4], aB0[4], aA1[4], aB1[4];

    // ---------------- L1 (K=32 MFMA + fp32 rank-1 for col 32) ----------------
    #pragma unroll
    for (int t=0;t<4;++t){
        float4 bv = *(const float4*)(bias0 + d*64 + 16*t + 4*hi);
        aA0[t] = (f4){bv.x,bv.y,bv.z,bv.w};
        aA1[t] = aA0[t];
    }
    __builtin_amdgcn_s_setprio(1);
    #pragma unroll
    for (int t=0;t<4;++t){
        sh8 af = *(const sh8*)&W0b[((16*t+nl)*32 + 8*hi)*2];
        aA0[t] = __builtin_amdgcn_mfma_f32_16x16x32_bf16(af, in0.s, aA0[t], 0,0,0);
        aA1[t] = __builtin_amdgcn_mfma_f32_16x16x32_bf16(af, in1.s, aA1[t], 0,0,0);
    }
    __builtin_amdgcn_s_setprio(0);

    // ---- E1: rank-1 + act -> bufA ; t1 = deriv1.*wcol -> bufB (both instances) ----
    float wc[4][4];
    {
        const float* wcolp = (const float*)(wsb + WCOL_OFF) + d*64;
        #pragma unroll
        for (int t=0;t<4;++t){
            float4 wv = *(const float4*)(wcolp + 16*t + 4*hi);
            wc[t][0]=wv.x; wc[t][1]=wv.y; wc[t][2]=wv.z; wc[t][3]=wv.w;
        }
    }
    #pragma unroll
    for (int t=0;t<4;++t){
        float v[4], tv[4];
        #pragma unroll
        for (int r=0;r<4;++r){
            float a = fmaf(wc[t][r], xx0, aA0[t][r]);
            v[r]  = fmaxf(a, SLOPE*a);
            tv[r] = (a >= 0.f) ? wc[t][r] : SLOPE*wc[t][r];
        }
        uint2 ph; ph.x = pk2(v[0],v[1]);  ph.y = pk2(v[2],v[3]);
        *(uint2*)&bufA[r0*128 + ((32*t + 8*hi) ^ rsw)] = ph;
        uint2 pt; pt.x = pk2(tv[0],tv[1]); pt.y = pk2(tv[2],tv[3]);
        *(uint2*)&bufB[r0*128 + ((32*t + 8*hi) ^ rsw)] = pt;
    }
    #pragma unroll
    for (int t=0;t<4;++t){
        float v[4], tv[4];
        #pragma unroll
        for (int r=0;r<4;++r){
            float a = fmaf(wc[t][r], xx1, aA1[t][r]);
            v[r]  = fmaxf(a, SLOPE*a);
            tv[r] = (a >= 0.f) ? wc[t][r] : SLOPE*wc[t][r];
        }
        uint2 ph; ph.x = pk2(v[0],v[1]);  ph.y = pk2(v[2],v[3]);
        *(uint2*)&bufA[r1*128 + ((32*t + 8*hi) ^ rsw)] = ph;
        uint2 pt; pt.x = pk2(tv[0],tv[1]); pt.y = pk2(tv[2],tv[3]);
        *(uint2*)&bufB[r1*128 + ((32*t + 8*hi) ^ rsw)] = pt;
    }

    // ---------------- G2: L2 fwd + T2 tangent, both instances, shared A-frags ----------------
    #pragma unroll
    for (int t=0;t<4;++t){
        float4 bv = *(const float4*)(bias1 + d*64 + 16*t + 4*hi);
        aA0[t] = (f4){bv.x,bv.y,bv.z,bv.w};
        aA1[t] = aA0[t];
        aB0[t] = (f4){0.f,0.f,0.f,0.f};
        aB1[t] = aB0[t];
    }
    __builtin_amdgcn_s_setprio(1);
    #pragma unroll
    for (int ks=0; ks<2; ++ks){
        sh8 fA0 = *(const sh8*)&bufA[r0*128 + ((64*ks + 16*hi) ^ rsw)];
        sh8 fB0 = *(const sh8*)&bufB[r0*128 + ((64*ks + 16*hi) ^ rsw)];
        sh8 fA1 = *(const sh8*)&bufA[r1*128 + ((64*ks + 16*hi) ^ rsw)];
        sh8 fB1 = *(const sh8*)&bufB[r1*128 + ((64*ks + 16*hi) ^ rsw)];
        #pragma unroll
        for (int t=0;t<4;++t){
            sh8 af = *(const sh8*)&W1b[((16*t+nl)*64 + 32*ks + 8*hi)*2];
            aA0[t] = __builtin_amdgcn_mfma_f32_16x16x32_bf16(af, fA0, aA0[t], 0,0,0);
            aB0[t] = __builtin_amdgcn_mfma_f32_16x16x32_bf16(af, fB0, aB0[t], 0,0,0);
            aA1[t] = __builtin_amdgcn_mfma_f32_16x16x32_bf16(af, fA1, aA1[t], 0,0,0);
            aB1[t] = __builtin_amdgcn_mfma_f32_16x16x32_bf16(af, fB1, aB1[t], 0,0,0);
        }
    }
    __builtin_amdgcn_s_setprio(0);
    // E2: h2 -> bufA, t2 -> bufB (both instances)
    #pragma unroll
    for (int t=0;t<4;++t){
        float v[4], tv[4];
        #pragma unroll
        for (int r=0;r<4;++r){
            float a = aA0[t][r];
            v[r] = fmaxf(a, SLOPE*a);
            float q = aB0[t][r];
            tv[r] = (a >= 0.f) ? q : SLOPE*q;
        }
        uint2 ph; ph.x = pk2(v[0],v[1]); ph.y = pk2(v[2],v[3]);
        *(uint2*)&bufA[r0*128 + ((32*t + 8*hi) ^ rsw)] = ph;
        uint2 pt; pt.x = pk2(tv[0],tv[1]); pt.y = pk2(tv[2],tv[3]);
        *(uint2*)&bufB[r0*128 + ((32*t + 8*hi) ^ rsw)] = pt;
    }
    #pragma unroll
    for (int t=0;t<4;++t){
        float v[4], tv[4];
        #pragma unroll
        for (int r=0;r<4;++r){
            float a = aA1[t][r];
            v[r] = fmaxf(a, SLOPE*a);
            float q = aB1[t][r];
            tv[r] = (a >= 0.f) ? q : SLOPE*q;
        }
        uint2 ph; ph.x = pk2(v[0],v[1]); ph.y = pk2(v[2],v[3]);
        *(uint2*)&bufA[r1*128 + ((32*t + 8*hi) ^ rsw)] = ph;
        uint2 pt; pt.x = pk2(tv[0],tv[1]); pt.y = pk2(tv[2],tv[3]);
        *(uint2*)&bufB[r1*128 + ((32*t + 8*hi) ^ rsw)] = pt;
    }

    // ---------------- G3: L3 fwd + T3 tangent, both instances ----------------
    #pragma unroll
    for (int t=0;t<4;++t){
        float4 bv = *(const float4*)(bias2 + d*64 + 16*t + 4*hi);
        aA0[t] = (f4){bv.x,bv.y,bv.z,bv.w};
        aA1[t] = aA0[t];
        aB0[t] = (f4){0.f,0.f,0.f,0.f};
        aB1[t] = aB0[t];
    }
    __builtin_amdgcn_s_setprio(1);
    #pragma unroll
    for (int ks=0; ks<2; ++ks){
        sh8 fA0 = *(const sh8*)&bufA[r0*128 + ((64*ks + 16*hi) ^ rsw)];
        sh8 fB0 = *(const sh8*)&bufB[r0*128 + ((64*ks + 16*hi) ^ rsw)];
        sh8 fA1 = *(const sh8*)&bufA[r1*128 + ((64*ks + 16*hi) ^ rsw)];
        sh8 fB1 = *(const sh8*)&bufB[r1*128 + ((64*ks + 16*hi) ^ rsw)];
        #pragma unroll
        for (int t=0;t<4;++t){
            sh8 af = *(const sh8*)&W2b[((16*t+nl)*64 + 32*ks + 8*hi)*2];
            aA0[t] = __builtin_amdgcn_mfma_f32_16x16x32_bf16(af, fA0, aA0[t], 0,0,0);
            aB0[t] = __builtin_amdgcn_mfma_f32_16x16x32_bf16(af, fB0, aB0[t], 0,0,0);
            aA1[t] = __builtin_amdgcn_mfma_f32_16x16x32_bf16(af, fA1, aA1[t], 0,0,0);
            aB1[t] = __builtin_amdgcn_mfma_f32_16x16x32_bf16(af, fB1, aB1[t], 0,0,0);
        }
    }
    __builtin_amdgcn_s_setprio(0);

    // ---------------- head + logdet (both instances) ----------------
    float res0 = 0.f, dres0 = 0.f, res1 = 0.f, dres1 = 0.f;
    #pragma unroll
    for (int t=0;t<4;++t){
        float4 ov = *(const float4*)(Wout + d*64 + 16*t + 4*hi);
        float wo[4] = {ov.x, ov.y, ov.z, ov.w};
        #pragma unroll
        for (int r=0;r<4;++r){
            float a0 = aA0[t][r];
            float h30 = fmaxf(a0, SLOPE*a0);
            res0 = fmaf(wo[r], h30, res0);
            float q0 = aB0[t][r];
            float tv0 = (a0 >= 0.f) ? q0 : SLOPE*q0;
            dres0 = fmaf(wo[r], tv0, dres0);

            float a1 = aA1[t][r];
            float h31 = fmaxf(a1, SLOPE*a1);
            res1 = fmaf(wo[r], h31, res1);
            float q1 = aB1[t][r];
            float tv1 = (a1 >= 0.f) ? q1 : SLOPE*q1;
            dres1 = fmaf(wo[r], tv1, dres1);
        }
    }
    res0  += __shfl_xor(res0, 16);  res0  += __shfl_xor(res0, 32);
    dres0 += __shfl_xor(dres0, 16); dres0 += __shfl_xor(dres0, 32);
    res1  += __shfl_xor(res1, 16);  res1  += __shfl_xor(res1, 32);
    dres1 += __shfl_xor(dres1, 16); dres1 += __shfl_xor(dres1, 32);
    const float bo = boutp[d];
    if (hi == 0){
        if (val0) resb[(size_t)(g*16 + d)*128 + r0] = res0 + bo;
        if (val1) resb[(size_t)(g*16 + d)*128 + r1] = res1 + bo;
    }

    float la0 = __logf(fabsf(dres0));
    float la1 = __logf(fabsf(dres1));

    // per-wave deterministic reduction (split by batch bucket)
    {
        int cb0 = (g*128) / NWIN;
        float v0 = (val0 && b0 == cb0     ? la0 : 0.f) + (val1 && b1 == cb0     ? la1 : 0.f);
        float v1 = (val0 && b0 == cb0 + 1 ? la0 : 0.f) + (val1 && b1 == cb0 + 1 ? la1 : 0.f);
        #pragma unroll
        for (int s = 1; s < 16; s <<= 1){
            v0 += __shfl_xor(v0, s);
            v1 += __shfl_xor(v1, s);
        }
        if (lane == 0){
            red[((size_t)(g*4 + w)*16 + d)*2 + 0] = v0;
            red[((size_t)(g*4 + w)*16 + d)*2 + 1] = v1;
        }
    }
}

// resb [g][d][row] -> out [n][d], fully coalesced writes
__global__ void scatter_out(const float* __restrict__ resb, float* __restrict__ out){
    int e = blockIdx.x*256 + threadIdx.x;   // 261120 total
    int n = e >> 4, d = e & 15;
    out[e] = resb[(size_t)((n >> 7)*16 + d)*128 + (n & 127)];
}

__global__ void final_red(const float* __restrict__ red, float* __restrict__ sld){
    __shared__ float pp[DDIM][16];
    const int b = blockIdx.x;
    const int tid = threadIdx.x;
    const int d = tid & 15, j = tid >> 4;
    float s = 0.f;
    for (int gw = j; gw < NG*4; gw += 16){
        int g = gw >> 2;
        int cb0 = (g*128)/NWIN;
        const float* r = red + ((size_t)gw*16 + d)*2;
        if (cb0     == b) s += r[0];
        if (cb0 + 1 == b) s += r[1];
    }
    pp[d][j] = s;
    __syncthreads();
    if (tid < DDIM){
        float a = 0.f;
        #pragma unroll
        for (int k=0;k<16;++k) a += pp[tid][k];
        pp[tid][0] = a;
    }
    __syncthreads();
    if (tid == 0){
        float a = 0.f;
        #pragma unroll
        for (int dd=0; dd<DDIM; ++dd) a += pp[dd][0];
        sld[b] = a;
    }
}

extern "C" void kernel_launch(void* const* d_in, const int* in_sizes, int n_in,
                              void* d_out, int out_size, void* d_ws, size_t ws_size,
                              hipStream_t stream) {
    const float* x    = (const float*)d_in[0];
    const float* W0   = (const float*)d_in[1];
    const float* b0   = (const float*)d_in[2];
    const float* W1   = (const float*)d_in[3];
    const float* b1   = (const float*)d_in[4];
    const float* W2   = (const float*)d_in[5];
    const float* b2   = (const float*)d_in[6];
    const float* Wout = (const float*)d_in[7];
    const float* bout = (const float*)d_in[8];
    float* out = (float*)d_out;
    unsigned char* wsb = (unsigned char*)d_ws;

    prep<<<(NPREP + 255)/256, 256, 0, stream>>>(W0, W1, W2, wsb);

    dim3 grid(NG, DDIM);
    mlp<<<grid, 256, 0, stream>>>(x, b0, b1, b2, Wout, bout, wsb,
                                  (float*)(wsb + RED_OFF),
                                  (float*)(wsb + RES_OFF));

    scatter_out<<<(NTOT*DDIM)/256, 256, 0, stream>>>((const float*)(wsb + RES_OFF), out);

    final_red<<<NB, 256, 0, stream>>>((const float*)(wsb + RED_OFF),
                                      out + (size_t)NTOT*DDIM);
}

// Round 8
// 45.776 us; speedup vs baseline: 2.9077x; 1.0451x over previous
//
#include <hip/hip_runtime.h>
#include <hip/hip_bf16.h>
#include <math.h>

#define NB 32
#define SEQT 512
#define DDIM 16
#define NWIN 510
#define NTOT (NB*NWIN)      // 16320
#define SLOPE 0.2f
#define NG 128              // groups of 128 windows (last one part-dummy)

typedef __attribute__((ext_vector_type(8))) short sh8;   // 8 bf16
typedef __attribute__((ext_vector_type(4))) float f4;

// ws byte offsets
#define W0B_OFF 0            // bf16 [16][64][32]   (k = 0..31 only)
#define W1B_OFF 65536        // bf16 [16][64][64]
#define W2B_OFF 196608       // bf16 [16][64][64]
#define WCOL_OFF 327680      // f32  [16][64]  = W0[d][h][32]
#define RED_OFF 331776       // f32  [512][16][2]   (65536 B)
#define NPREP 164864

static __device__ __forceinline__ unsigned short bfb(float f){
    union { __hip_bfloat16 h; unsigned short u; } cv;
    cv.h = __float2bfloat16(f);
    return cv.u;
}
static __device__ __forceinline__ unsigned pk2(float a, float b){
    return (unsigned)bfb(a) | ((unsigned)bfb(b) << 16);
}

__global__ void prep(const float* __restrict__ W0, const float* __restrict__ W1,
                     const float* __restrict__ W2, unsigned char* __restrict__ wsb){
    int e = blockIdx.x*256 + threadIdx.x;
    if (e < 32768){
        unsigned short* W0b = (unsigned short*)(wsb + W0B_OFF);
        int d = e >> 11, r = e & 2047, h = r >> 5, k = r & 31;
        W0b[e] = bfb(W0[(d*64 + h)*33 + k]);
    } else if (e < 98304){
        ((unsigned short*)(wsb + W1B_OFF))[e - 32768] = bfb(W1[e - 32768]);
    } else if (e < 163840){
        ((unsigned short*)(wsb + W2B_OFF))[e - 98304] = bfb(W2[e - 98304]);
    } else if (e < NPREP){
        int i = e - 163840;
        int d = i >> 6, h = i & 63;
        ((float*)(wsb + WCOL_OFF))[i] = W0[(d*64 + h)*33 + 32];
    }
}

__global__ __launch_bounds__(256, 3) void mlp(
    const float* __restrict__ x,
    const float* __restrict__ bias0, const float* __restrict__ bias1,
    const float* __restrict__ bias2,
    const float* __restrict__ Wout, const float* __restrict__ boutp,
    const unsigned char* __restrict__ wsb,
    float* __restrict__ red, float* __restrict__ out)
{
    // barrier-free: wave w owns rows [32w, 32w+32) of bufA/bufB.
    // each wave runs TWO independent 16-window instances for intra-wave ILP.
    __shared__ __align__(16) unsigned char bufA[128*128];   // h1 -> h2 (in-place), 16 KB
    __shared__ __align__(16) unsigned char bufB[128*128];   // t1 -> t2 (in-place), 16 KB

    const int tid  = threadIdx.x;
    const int lane = tid & 63;
    const int w    = tid >> 6;
    const int nl   = lane & 15;
    const int hi   = lane >> 4;
    const int rsw  = (nl & 7) << 4;

    // XCD-local decode: bid = (g&7) + 8*(d + 16*(g>>3))
    // -> all 16 d-blocks of window-group g share bid%8 (same XCD under
    //    round-robin dispatch), so out-lines are single-XCD-owned.
    const int bid = blockIdx.x;
    const int d   = (bid >> 3) & 15;
    const int g   = ((bid >> 7) << 3) | (bid & 7);

    const int r0 = 32*w + nl;         // instance-0 row
    const int r1 = r0 + 16;           // instance-1 row
    const int n0 = g*128 + r0;
    const int n1 = n0 + 16;
    const bool val0 = (n0 < NTOT), val1 = (n1 < NTOT);
    const int ne0 = val0 ? n0 : NTOT-1;
    const int ne1 = val1 ? n1 : NTOT-1;
    const int b0 = ne0 / NWIN, t0 = ne0 - b0*NWIN;
    const int b1 = ne1 / NWIN, t1 = ne1 - b1*NWIN;

    // ---- L1 B-fragments straight from global (f32 -> bf16, no LDS) ----
    const float* gp0 = x + (size_t)(b0*SEQT + t0)*DDIM + 8*hi;
    const float* gp1 = x + (size_t)(b1*SEQT + t1)*DDIM + 8*hi;
    float4 p00 = ((const float4*)gp0)[0], p01 = ((const float4*)gp0)[1];
    float4 p10 = ((const float4*)gp1)[0], p11 = ((const float4*)gp1)[1];
    union { uint4 u; sh8 s; } in0, in1;
    in0.u.x = pk2(p00.x,p00.y); in0.u.y = pk2(p00.z,p00.w);
    in0.u.z = pk2(p01.x,p01.y); in0.u.w = pk2(p01.z,p01.w);
    in1.u.x = pk2(p10.x,p10.y); in1.u.y = pk2(p10.z,p10.w);
    in1.u.z = pk2(p11.x,p11.y); in1.u.w = pk2(p11.z,p11.w);

    const float xx0 = x[(size_t)(b0*SEQT + t0 + 2)*DDIM + d];
    const float xx1 = x[(size_t)(b1*SEQT + t1 + 2)*DDIM + d];

    const unsigned char* W0b = wsb + W0B_OFF + d*4096;
    const unsigned char* W1b = wsb + W1B_OFF + d*8192;
    const unsigned char* W2b = wsb + W2B_OFF + d*8192;

    f4 aA0[4], aB0[4], aA1[4], aB1[4];

    // ---------------- L1 (K=32 MFMA + fp32 rank-1 for col 32) ----------------
    #pragma unroll
    for (int t=0;t<4;++t){
        float4 bv = *(const float4*)(bias0 + d*64 + 16*t + 4*hi);
        aA0[t] = (f4){bv.x,bv.y,bv.z,bv.w};
        aA1[t] = aA0[t];
    }
    __builtin_amdgcn_s_setprio(1);
    #pragma unroll
    for (int t=0;t<4;++t){
        sh8 af = *(const sh8*)&W0b[((16*t+nl)*32 + 8*hi)*2];
        aA0[t] = __builtin_amdgcn_mfma_f32_16x16x32_bf16(af, in0.s, aA0[t], 0,0,0);
        aA1[t] = __builtin_amdgcn_mfma_f32_16x16x32_bf16(af, in1.s, aA1[t], 0,0,0);
    }
    __builtin_amdgcn_s_setprio(0);

    // ---- E1: rank-1 + act -> bufA ; t1 = deriv1.*wcol -> bufB (both instances) ----
    float wc[4][4];
    {
        const float* wcolp = (const float*)(wsb + WCOL_OFF) + d*64;
        #pragma unroll
        for (int t=0;t<4;++t){
            float4 wv = *(const float4*)(wcolp + 16*t + 4*hi);
            wc[t][0]=wv.x; wc[t][1]=wv.y; wc[t][2]=wv.z; wc[t][3]=wv.w;
        }
    }
    #pragma unroll
    for (int t=0;t<4;++t){
        float v[4], tv[4];
        #pragma unroll
        for (int r=0;r<4;++r){
            float a = fmaf(wc[t][r], xx0, aA0[t][r]);
            v[r]  = fmaxf(a, SLOPE*a);
            tv[r] = (a >= 0.f) ? wc[t][r] : SLOPE*wc[t][r];
        }
        uint2 ph; ph.x = pk2(v[0],v[1]);  ph.y = pk2(v[2],v[3]);
        *(uint2*)&bufA[r0*128 + ((32*t + 8*hi) ^ rsw)] = ph;
        uint2 pt; pt.x = pk2(tv[0],tv[1]); pt.y = pk2(tv[2],tv[3]);
        *(uint2*)&bufB[r0*128 + ((32*t + 8*hi) ^ rsw)] = pt;
    }
    #pragma unroll
    for (int t=0;t<4;++t){
        float v[4], tv[4];
        #pragma unroll
        for (int r=0;r<4;++r){
            float a = fmaf(wc[t][r], xx1, aA1[t][r]);
            v[r]  = fmaxf(a, SLOPE*a);
            tv[r] = (a >= 0.f) ? wc[t][r] : SLOPE*wc[t][r];
        }
        uint2 ph; ph.x = pk2(v[0],v[1]);  ph.y = pk2(v[2],v[3]);
        *(uint2*)&bufA[r1*128 + ((32*t + 8*hi) ^ rsw)] = ph;
        uint2 pt; pt.x = pk2(tv[0],tv[1]); pt.y = pk2(tv[2],tv[3]);
        *(uint2*)&bufB[r1*128 + ((32*t + 8*hi) ^ rsw)] = pt;
    }

    // ---------------- G2: L2 fwd + T2 tangent, both instances, shared A-frags ----------------
    #pragma unroll
    for (int t=0;t<4;++t){
        float4 bv = *(const float4*)(bias1 + d*64 + 16*t + 4*hi);
        aA0[t] = (f4){bv.x,bv.y,bv.z,bv.w};
        aA1[t] = aA0[t];
        aB0[t] = (f4){0.f,0.f,0.f,0.f};
        aB1[t] = aB0[t];
    }
    __builtin_amdgcn_s_setprio(1);
    #pragma unroll
    for (int ks=0; ks<2; ++ks){
        sh8 fA0 = *(const sh8*)&bufA[r0*128 + ((64*ks + 16*hi) ^ rsw)];
        sh8 fB0 = *(const sh8*)&bufB[r0*128 + ((64*ks + 16*hi) ^ rsw)];
        sh8 fA1 = *(const sh8*)&bufA[r1*128 + ((64*ks + 16*hi) ^ rsw)];
        sh8 fB1 = *(const sh8*)&bufB[r1*128 + ((64*ks + 16*hi) ^ rsw)];
        #pragma unroll
        for (int t=0;t<4;++t){
            sh8 af = *(const sh8*)&W1b[((16*t+nl)*64 + 32*ks + 8*hi)*2];
            aA0[t] = __builtin_amdgcn_mfma_f32_16x16x32_bf16(af, fA0, aA0[t], 0,0,0);
            aB0[t] = __builtin_amdgcn_mfma_f32_16x16x32_bf16(af, fB0, aB0[t], 0,0,0);
            aA1[t] = __builtin_amdgcn_mfma_f32_16x16x32_bf16(af, fA1, aA1[t], 0,0,0);
            aB1[t] = __builtin_amdgcn_mfma_f32_16x16x32_bf16(af, fB1, aB1[t], 0,0,0);
        }
    }
    __builtin_amdgcn_s_setprio(0);
    // E2: h2 -> bufA, t2 -> bufB (both instances)
    #pragma unroll
    for (int t=0;t<4;++t){
        float v[4], tv[4];
        #pragma unroll
        for (int r=0;r<4;++r){
            float a = aA0[t][r];
            v[r] = fmaxf(a, SLOPE*a);
            float q = aB0[t][r];
            tv[r] = (a >= 0.f) ? q : SLOPE*q;
        }
        uint2 ph; ph.x = pk2(v[0],v[1]); ph.y = pk2(v[2],v[3]);
        *(uint2*)&bufA[r0*128 + ((32*t + 8*hi) ^ rsw)] = ph;
        uint2 pt; pt.x = pk2(tv[0],tv[1]); pt.y = pk2(tv[2],tv[3]);
        *(uint2*)&bufB[r0*128 + ((32*t + 8*hi) ^ rsw)] = pt;
    }
    #pragma unroll
    for (int t=0;t<4;++t){
        float v[4], tv[4];
        #pragma unroll
        for (int r=0;r<4;++r){
            float a = aA1[t][r];
            v[r] = fmaxf(a, SLOPE*a);
            float q = aB1[t][r];
            tv[r] = (a >= 0.f) ? q : SLOPE*q;
        }
        uint2 ph; ph.x = pk2(v[0],v[1]); ph.y = pk2(v[2],v[3]);
        *(uint2*)&bufA[r1*128 + ((32*t + 8*hi) ^ rsw)] = ph;
        uint2 pt; pt.x = pk2(tv[0],tv[1]); pt.y = pk2(tv[2],tv[3]);
        *(uint2*)&bufB[r1*128 + ((32*t + 8*hi) ^ rsw)] = pt;
    }

    // ---------------- G3: L3 fwd + T3 tangent, both instances ----------------
    #pragma unroll
    for (int t=0;t<4;++t){
        float4 bv = *(const float4*)(bias2 + d*64 + 16*t + 4*hi);
        aA0[t] = (f4){bv.x,bv.y,bv.z,bv.w};
        aA1[t] = aA0[t];
        aB0[t] = (f4){0.f,0.f,0.f,0.f};
        aB1[t] = aB0[t];
    }
    __builtin_amdgcn_s_setprio(1);
    #pragma unroll
    for (int ks=0; ks<2; ++ks){
        sh8 fA0 = *(const sh8*)&bufA[r0*128 + ((64*ks + 16*hi) ^ rsw)];
        sh8 fB0 = *(const sh8*)&bufB[r0*128 + ((64*ks + 16*hi) ^ rsw)];
        sh8 fA1 = *(const sh8*)&bufA[r1*128 + ((64*ks + 16*hi) ^ rsw)];
        sh8 fB1 = *(const sh8*)&bufB[r1*128 + ((64*ks + 16*hi) ^ rsw)];
        #pragma unroll
        for (int t=0;t<4;++t){
            sh8 af = *(const sh8*)&W2b[((16*t+nl)*64 + 32*ks + 8*hi)*2];
            aA0[t] = __builtin_amdgcn_mfma_f32_16x16x32_bf16(af, fA0, aA0[t], 0,0,0);
            aB0[t] = __builtin_amdgcn_mfma_f32_16x16x32_bf16(af, fB0, aB0[t], 0,0,0);
            aA1[t] = __builtin_amdgcn_mfma_f32_16x16x32_bf16(af, fA1, aA1[t], 0,0,0);
            aB1[t] = __builtin_amdgcn_mfma_f32_16x16x32_bf16(af, fB1, aB1[t], 0,0,0);
        }
    }
    __builtin_amdgcn_s_setprio(0);

    // ---------------- head + logdet (both instances) ----------------
    float res0 = 0.f, dres0 = 0.f, res1 = 0.f, dres1 = 0.f;
    #pragma unroll
    for (int t=0;t<4;++t){
        float4 ov = *(const float4*)(Wout + d*64 + 16*t + 4*hi);
        float wo[4] = {ov.x, ov.y, ov.z, ov.w};
        #pragma unroll
        for (int r=0;r<4;++r){
            float a0 = aA0[t][r];
            float h30 = fmaxf(a0, SLOPE*a0);
            res0 = fmaf(wo[r], h30, res0);
            float q0 = aB0[t][r];
            float tv0 = (a0 >= 0.f) ? q0 : SLOPE*q0;
            dres0 = fmaf(wo[r], tv0, dres0);

            float a1 = aA1[t][r];
            float h31 = fmaxf(a1, SLOPE*a1);
            res1 = fmaf(wo[r], h31, res1);
            float q1 = aB1[t][r];
            float tv1 = (a1 >= 0.f) ? q1 : SLOPE*q1;
            dres1 = fmaf(wo[r], tv1, dres1);
        }
    }
    res0  += __shfl_xor(res0, 16);  res0  += __shfl_xor(res0, 32);
    dres0 += __shfl_xor(dres0, 16); dres0 += __shfl_xor(dres0, 32);
    res1  += __shfl_xor(res1, 16);  res1  += __shfl_xor(res1, 32);
    dres1 += __shfl_xor(dres1, 16); dres1 += __shfl_xor(dres1, 32);
    const float bo = boutp[d];
    // direct store: all 16 d-writers of each out-line share this XCD
    if (hi == 0){
        if (val0) out[(size_t)n0*DDIM + d] = res0 + bo;
        if (val1) out[(size_t)n1*DDIM + d] = res1 + bo;
    }

    float la0 = __logf(fabsf(dres0));
    float la1 = __logf(fabsf(dres1));

    // per-wave deterministic reduction (split by batch bucket)
    {
        int cb0 = (g*128) / NWIN;
        float v0 = (val0 && b0 == cb0     ? la0 : 0.f) + (val1 && b1 == cb0     ? la1 : 0.f);
        float v1 = (val0 && b0 == cb0 + 1 ? la0 : 0.f) + (val1 && b1 == cb0 + 1 ? la1 : 0.f);
        #pragma unroll
        for (int s = 1; s < 16; s <<= 1){
            v0 += __shfl_xor(v0, s);
            v1 += __shfl_xor(v1, s);
        }
        if (lane == 0){
            red[((size_t)(g*4 + w)*16 + d)*2 + 0] = v0;
            red[((size_t)(g*4 + w)*16 + d)*2 + 1] = v1;
        }
    }
}

__global__ void final_red(const float* __restrict__ red, float* __restrict__ sld){
    __shared__ float pp[DDIM][16];
    const int b = blockIdx.x;
    const int tid = threadIdx.x;
    const int d = tid & 15, j = tid >> 4;
    float s = 0.f;
    for (int gw = j; gw < NG*4; gw += 16){
        int g = gw >> 2;
        int cb0 = (g*128)/NWIN;
        const float* r = red + ((size_t)gw*16 + d)*2;
        if (cb0     == b) s += r[0];
        if (cb0 + 1 == b) s += r[1];
    }
    pp[d][j] = s;
    __syncthreads();
    if (tid < DDIM){
        float a = 0.f;
        #pragma unroll
        for (int k=0;k<16;++k) a += pp[tid][k];
        pp[tid][0] = a;
    }
    __syncthreads();
    if (tid == 0){
        float a = 0.f;
        #pragma unroll
        for (int dd=0; dd<DDIM; ++dd) a += pp[dd][0];
        sld[b] = a;
    }
}

extern "C" void kernel_launch(void* const* d_in, const int* in_sizes, int n_in,
                              void* d_out, int out_size, void* d_ws, size_t ws_size,
                              hipStream_t stream) {
    const float* x    = (const float*)d_in[0];
    const float* W0   = (const float*)d_in[1];
    const float* b0   = (const float*)d_in[2];
    const float* W1   = (const float*)d_in[3];
    const float* b1   = (const float*)d_in[4];
    const float* W2   = (const float*)d_in[5];
    const float* b2   = (const float*)d_in[6];
    const float* Wout = (const float*)d_in[7];
    const float* bout = (const float*)d_in[8];
    float* out = (float*)d_out;
    unsigned char* wsb = (unsigned char*)d_ws;

    prep<<<(NPREP + 255)/256, 256, 0, stream>>>(W0, W1, W2, wsb);

    mlp<<<NG*DDIM, 256, 0, stream>>>(x, b0, b1, b2, Wout, bout, wsb,
                                     (float*)(wsb + RED_OFF), out);

    final_red<<<NB, 256, 0, stream>>>((const float*)(wsb + RED_OFF),
                                      out + (size_t)NTOT*DDIM);
}

// Round 9
// 42.756 us; speedup vs baseline: 3.1130x; 1.0706x over previous
//
#include <hip/hip_runtime.h>
#include <hip/hip_bf16.h>
#include <math.h>

#define NB 32
#define SEQT 512
#define DDIM 16
#define NWIN 510
#define NTOT (NB*NWIN)      // 16320
#define SLOPE 0.2f
#define NI 3                // instances per wave
#define GW 192              // windows per block (4 waves * 3 inst * 16)
#define NGR 85              // real groups: 85*192 = 16320 exactly
#define NGP 88              // padded to multiple of 8 for XCD mapping

typedef __attribute__((ext_vector_type(8))) short sh8;   // 8 bf16
typedef __attribute__((ext_vector_type(4))) float f4;

// ws byte offsets
#define W0B_OFF 0            // bf16 [16][64][32]   (k = 0..31 only)
#define W1B_OFF 65536        // bf16 [16][64][64]
#define W2B_OFF 196608       // bf16 [16][64][64]
#define WCOL_OFF 327680      // f32  [16][64]  = W0[d][h][32]
#define RED_OFF 331776       // f32  [340][16][2]
#define NPREP 164864

static __device__ __forceinline__ unsigned short bfb(float f){
    union { __hip_bfloat16 h; unsigned short u; } cv;
    cv.h = __float2bfloat16(f);
    return cv.u;
}
static __device__ __forceinline__ unsigned pk2(float a, float b){
    return (unsigned)bfb(a) | ((unsigned)bfb(b) << 16);
}

__global__ void prep(const float* __restrict__ W0, const float* __restrict__ W1,
                     const float* __restrict__ W2, unsigned char* __restrict__ wsb){
    int e = blockIdx.x*256 + threadIdx.x;
    if (e < 32768){
        unsigned short* W0b = (unsigned short*)(wsb + W0B_OFF);
        int d = e >> 11, r = e & 2047, h = r >> 5, k = r & 31;
        W0b[e] = bfb(W0[(d*64 + h)*33 + k]);
    } else if (e < 98304){
        ((unsigned short*)(wsb + W1B_OFF))[e - 32768] = bfb(W1[e - 32768]);
    } else if (e < 163840){
        ((unsigned short*)(wsb + W2B_OFF))[e - 98304] = bfb(W2[e - 98304]);
    } else if (e < NPREP){
        int i = e - 163840;
        int d = i >> 6, h = i & 63;
        ((float*)(wsb + WCOL_OFF))[i] = W0[(d*64 + h)*33 + 32];
    }
}

__global__ __launch_bounds__(256, 3) void mlp(
    const float* __restrict__ x,
    const float* __restrict__ bias0, const float* __restrict__ bias1,
    const float* __restrict__ bias2,
    const float* __restrict__ Wout, const float* __restrict__ boutp,
    const unsigned char* __restrict__ wsb,
    float* __restrict__ red, float* __restrict__ out)
{
    // barrier-free: wave w owns rows [48w, 48w+48). 3 instances per wave.
    __shared__ __align__(16) unsigned char bufA[GW*128];   // h1 -> h2 (in-place), 24 KB
    __shared__ __align__(16) unsigned char bufB[GW*128];   // t1 -> t2 (in-place), 24 KB

    const int tid  = threadIdx.x;
    const int lane = tid & 63;
    const int w    = tid >> 6;
    const int nl   = lane & 15;
    const int hi   = lane >> 4;
    const int rsw  = (nl & 7) << 4;

    // XCD-local decode: bid = (g&7) + 8*d + 128*(g>>3); all 16 d-blocks of a
    // group share bid%8 (same XCD under round-robin dispatch).
    const int bid = blockIdx.x;
    const int d   = (bid >> 3) & 15;
    const int g   = ((bid >> 7) << 3) | (bid & 7);
    if (g >= NGR) return;            // padded dummies

    const unsigned char* W0b = wsb + W0B_OFF + d*4096;
    const unsigned char* W1b = wsb + W1B_OFF + d*8192;
    const unsigned char* W2b = wsb + W2B_OFF + d*8192;

    int   bb[NI], ttv[NI];
    float xxv[NI];
    union { uint4 u; sh8 s; } in[NI];
    #pragma unroll
    for (int i=0;i<NI;++i){
        int n = g*GW + 48*w + nl + 16*i;
        int b = n / NWIN, t = n - b*NWIN;
        bb[i] = b; ttv[i] = t;
        const float* gp = x + (size_t)(b*SEQT + t)*DDIM + 8*hi;
        float4 p0 = ((const float4*)gp)[0];
        float4 p1 = ((const float4*)gp)[1];
        in[i].u.x = pk2(p0.x,p0.y); in[i].u.y = pk2(p0.z,p0.w);
        in[i].u.z = pk2(p1.x,p1.y); in[i].u.w = pk2(p1.z,p1.w);
        xxv[i] = x[(size_t)(b*SEQT + t + 2)*DDIM + d];
    }

    f4 aA[NI][4], aB[NI][4];

    // ---------------- L1 (K=32 MFMA + fp32 rank-1 for col 32) ----------------
    #pragma unroll
    for (int t=0;t<4;++t){
        float4 bv = *(const float4*)(bias0 + d*64 + 16*t + 4*hi);
        #pragma unroll
        for (int i=0;i<NI;++i) aA[i][t] = (f4){bv.x,bv.y,bv.z,bv.w};
    }
    __builtin_amdgcn_s_setprio(1);
    #pragma unroll
    for (int t=0;t<4;++t){
        sh8 af = *(const sh8*)&W0b[((16*t+nl)*32 + 8*hi)*2];
        #pragma unroll
        for (int i=0;i<NI;++i)
            aA[i][t] = __builtin_amdgcn_mfma_f32_16x16x32_bf16(af, in[i].s, aA[i][t], 0,0,0);
    }
    __builtin_amdgcn_s_setprio(0);

    // ---- E1: rank-1 + act -> bufA ; t1 = deriv1.*wcol -> bufB ----
    {
        const float* wcolp = (const float*)(wsb + WCOL_OFF) + d*64;
        #pragma unroll
        for (int t=0;t<4;++t){
            float4 wv = *(const float4*)(wcolp + 16*t + 4*hi);
            float wc[4] = {wv.x, wv.y, wv.z, wv.w};
            #pragma unroll
            for (int i=0;i<NI;++i){
                const int row = 48*w + nl + 16*i;
                float v[4], tv[4];
                #pragma unroll
                for (int r=0;r<4;++r){
                    float a = fmaf(wc[r], xxv[i], aA[i][t][r]);
                    v[r]  = fmaxf(a, SLOPE*a);
                    tv[r] = (a >= 0.f) ? wc[r] : SLOPE*wc[r];
                }
                uint2 ph; ph.x = pk2(v[0],v[1]);  ph.y = pk2(v[2],v[3]);
                *(uint2*)&bufA[row*128 + ((32*t + 8*hi) ^ rsw)] = ph;
                uint2 pt; pt.x = pk2(tv[0],tv[1]); pt.y = pk2(tv[2],tv[3]);
                *(uint2*)&bufB[row*128 + ((32*t + 8*hi) ^ rsw)] = pt;
            }
        }
    }

    // ---------------- G2: L2 fwd + T2 tangent, shared A-frags ----------------
    #pragma unroll
    for (int t=0;t<4;++t){
        float4 bv = *(const float4*)(bias1 + d*64 + 16*t + 4*hi);
        #pragma unroll
        for (int i=0;i<NI;++i){
            aA[i][t] = (f4){bv.x,bv.y,bv.z,bv.w};
            aB[i][t] = (f4){0.f,0.f,0.f,0.f};
        }
    }
    __builtin_amdgcn_s_setprio(1);
    #pragma unroll
    for (int ks=0; ks<2; ++ks){
        sh8 fA[NI], fB[NI];
        #pragma unroll
        for (int i=0;i<NI;++i){
            const int row = 48*w + nl + 16*i;
            fA[i] = *(const sh8*)&bufA[row*128 + ((64*ks + 16*hi) ^ rsw)];
            fB[i] = *(const sh8*)&bufB[row*128 + ((64*ks + 16*hi) ^ rsw)];
        }
        #pragma unroll
        for (int t=0;t<4;++t){
            sh8 af = *(const sh8*)&W1b[((16*t+nl)*64 + 32*ks + 8*hi)*2];
            #pragma unroll
            for (int i=0;i<NI;++i){
                aA[i][t] = __builtin_amdgcn_mfma_f32_16x16x32_bf16(af, fA[i], aA[i][t], 0,0,0);
                aB[i][t] = __builtin_amdgcn_mfma_f32_16x16x32_bf16(af, fB[i], aB[i][t], 0,0,0);
            }
        }
    }
    __builtin_amdgcn_s_setprio(0);
    // E2: h2 -> bufA, t2 -> bufB
    #pragma unroll
    for (int i=0;i<NI;++i){
        const int row = 48*w + nl + 16*i;
        #pragma unroll
        for (int t=0;t<4;++t){
            float v[4], tv[4];
            #pragma unroll
            for (int r=0;r<4;++r){
                float a = aA[i][t][r];
                v[r] = fmaxf(a, SLOPE*a);
                float q = aB[i][t][r];
                tv[r] = (a >= 0.f) ? q : SLOPE*q;
            }
            uint2 ph; ph.x = pk2(v[0],v[1]); ph.y = pk2(v[2],v[3]);
            *(uint2*)&bufA[row*128 + ((32*t + 8*hi) ^ rsw)] = ph;
            uint2 pt; pt.x = pk2(tv[0],tv[1]); pt.y = pk2(tv[2],tv[3]);
            *(uint2*)&bufB[row*128 + ((32*t + 8*hi) ^ rsw)] = pt;
        }
    }

    // ---------------- G3: L3 fwd + T3 tangent ----------------
    #pragma unroll
    for (int t=0;t<4;++t){
        float4 bv = *(const float4*)(bias2 + d*64 + 16*t + 4*hi);
        #pragma unroll
        for (int i=0;i<NI;++i){
            aA[i][t] = (f4){bv.x,bv.y,bv.z,bv.w};
            aB[i][t] = (f4){0.f,0.f,0.f,0.f};
        }
    }
    __builtin_amdgcn_s_setprio(1);
    #pragma unroll
    for (int ks=0; ks<2; ++ks){
        sh8 fA[NI], fB[NI];
        #pragma unroll
        for (int i=0;i<NI;++i){
            const int row = 48*w + nl + 16*i;
            fA[i] = *(const sh8*)&bufA[row*128 + ((64*ks + 16*hi) ^ rsw)];
            fB[i] = *(const sh8*)&bufB[row*128 + ((64*ks + 16*hi) ^ rsw)];
        }
        #pragma unroll
        for (int t=0;t<4;++t){
            sh8 af = *(const sh8*)&W2b[((16*t+nl)*64 + 32*ks + 8*hi)*2];
            #pragma unroll
            for (int i=0;i<NI;++i){
                aA[i][t] = __builtin_amdgcn_mfma_f32_16x16x32_bf16(af, fA[i], aA[i][t], 0,0,0);
                aB[i][t] = __builtin_amdgcn_mfma_f32_16x16x32_bf16(af, fB[i], aB[i][t], 0,0,0);
            }
        }
    }
    __builtin_amdgcn_s_setprio(0);

    // ---------------- head + logdet ----------------
    float res[NI], dres[NI];
    #pragma unroll
    for (int i=0;i<NI;++i){ res[i] = 0.f; dres[i] = 0.f; }
    #pragma unroll
    for (int t=0;t<4;++t){
        float4 ov = *(const float4*)(Wout + d*64 + 16*t + 4*hi);
        float wo[4] = {ov.x, ov.y, ov.z, ov.w};
        #pragma unroll
        for (int i=0;i<NI;++i){
            #pragma unroll
            for (int r=0;r<4;++r){
                float a  = aA[i][t][r];
                float h3 = fmaxf(a, SLOPE*a);
                res[i] = fmaf(wo[r], h3, res[i]);
                float q  = aB[i][t][r];
                float tv = (a >= 0.f) ? q : SLOPE*q;
                dres[i] = fmaf(wo[r], tv, dres[i]);
            }
        }
    }
    const float bo = boutp[d];
    float la[NI];
    #pragma unroll
    for (int i=0;i<NI;++i){
        res[i]  += __shfl_xor(res[i], 16);  res[i]  += __shfl_xor(res[i], 32);
        dres[i] += __shfl_xor(dres[i], 16); dres[i] += __shfl_xor(dres[i], 32);
        la[i] = __logf(fabsf(dres[i]));
    }
    if (hi == 0){
        #pragma unroll
        for (int i=0;i<NI;++i){
            int n = g*GW + 48*w + nl + 16*i;
            out[(size_t)n*DDIM + d] = res[i] + bo;
        }
    }

    // per-wave deterministic reduction (split by batch bucket)
    {
        int cb0 = (g*GW) / NWIN;
        float v0 = 0.f, v1 = 0.f;
        #pragma unroll
        for (int i=0;i<NI;++i){
            v0 += (bb[i] == cb0    ) ? la[i] : 0.f;
            v1 += (bb[i] == cb0 + 1) ? la[i] : 0.f;
        }
        #pragma unroll
        for (int s = 1; s < 16; s <<= 1){
            v0 += __shfl_xor(v0, s);
            v1 += __shfl_xor(v1, s);
        }
        if (lane == 0){
            red[((size_t)(g*4 + w)*16 + d)*2 + 0] = v0;
            red[((size_t)(g*4 + w)*16 + d)*2 + 1] = v1;
        }
    }
}

__global__ void final_red(const float* __restrict__ red, float* __restrict__ sld){
    __shared__ float pp[DDIM][16];
    const int b = blockIdx.x;
    const int tid = threadIdx.x;
    const int d = tid & 15, j = tid >> 4;
    float s = 0.f;
    for (int gw = j; gw < NGR*4; gw += 16){
        int g = gw >> 2;
        int cb0 = (g*GW)/NWIN;
        const float* r = red + ((size_t)gw*16 + d)*2;
        if (cb0     == b) s += r[0];
        if (cb0 + 1 == b) s += r[1];
    }
    pp[d][j] = s;
    __syncthreads();
    if (tid < DDIM){
        float a = 0.f;
        #pragma unroll
        for (int k=0;k<16;++k) a += pp[tid][k];
        pp[tid][0] = a;
    }
    __syncthreads();
    if (tid == 0){
        float a = 0.f;
        #pragma unroll
        for (int dd=0; dd<DDIM; ++dd) a += pp[dd][0];
        sld[b] = a;
    }
}

extern "C" void kernel_launch(void* const* d_in, const int* in_sizes, int n_in,
                              void* d_out, int out_size, void* d_ws, size_t ws_size,
                              hipStream_t stream) {
    const float* x    = (const float*)d_in[0];
    const float* W0   = (const float*)d_in[1];
    const float* b0   = (const float*)d_in[2];
    const float* W1   = (const float*)d_in[3];
    const float* b1   = (const float*)d_in[4];
    const float* W2   = (const float*)d_in[5];
    const float* b2   = (const float*)d_in[6];
    const float* Wout = (const float*)d_in[7];
    const float* bout = (const float*)d_in[8];
    float* out = (float*)d_out;
    unsigned char* wsb = (unsigned char*)d_ws;

    prep<<<(NPREP + 255)/256, 256, 0, stream>>>(W0, W1, W2, wsb);

    mlp<<<NGP*DDIM, 256, 0, stream>>>(x, b0, b1, b2, Wout, bout, wsb,
                                      (float*)(wsb + RED_OFF), out);

    final_red<<<NB, 256, 0, stream>>>((const float*)(wsb + RED_OFF),
                                      out + (size_t)NTOT*DDIM);
}